// Round 4
// baseline (520.300 us; speedup 1.0000x reference)
//
#include <hip/hip_runtime.h>
#include <hip/hip_bf16.h>
#include <math.h>

// GAT 2-layer fused pipeline for MI355X (gfx950).
// Dims per reference: D_IN=D_H=128, D_OUT=64, SLOPE=0.2. All math fp32.
//
// Round-4 changes:
//  - gemm: software-pipelined W stream (double-buffered register prefetch at
//    2-k granularity) so W-load latency hides under FMAs; ROWS 64->32 for
//    ~6 blocks/CU (1563 blocks). Round-3 version was load->wait->FMA serial
//    (VALUBusy 23%, 96us vs 21us FMA floor).
//  - gat_agg unchanged (scalar CSR walk via readfirstlane, x4 unroll, DPP).

#define SLOPE 0.2f

__device__ __forceinline__ float gelu_erf(float x) {
    return 0.5f * x * (1.0f + erff(x * 0.70710678118654752f));
}

// Full-wave (64-lane) f32 sum via DPP; result broadcast via readlane 63.
__device__ __forceinline__ float wave_sum_bcast(float x) {
    x += __int_as_float(__builtin_amdgcn_update_dpp(0, __float_as_int(x), 0x111, 0xF, 0xF, true));
    x += __int_as_float(__builtin_amdgcn_update_dpp(0, __float_as_int(x), 0x112, 0xF, 0xF, true));
    x += __int_as_float(__builtin_amdgcn_update_dpp(0, __float_as_int(x), 0x114, 0xF, 0xF, true));
    x += __int_as_float(__builtin_amdgcn_update_dpp(0, __float_as_int(x), 0x118, 0xF, 0xF, true));
    x += __int_as_float(__builtin_amdgcn_update_dpp(0, __float_as_int(x), 0x142, 0xF, 0xF, true));
    x += __int_as_float(__builtin_amdgcn_update_dpp(0, __float_as_int(x), 0x143, 0xF, 0xF, true));
    return __int_as_float(__builtin_amdgcn_readlane(__float_as_int(x), 63));
}

// ---------------- GEMM: out[N,C] = act(A[N,128] @ W[128,C] + bias) ----------
// 256 threads, 32 rows/block; thread: 2 rows x (COLS4*4) cols x (1|2 outputs).
// W streamed from global with 2-k double-buffered register prefetch.
template <int C, int ACT, bool DUAL>
__global__ __launch_bounds__(256) void gemm_k128(
    const float* __restrict__ A,
    const float* __restrict__ W1, const float* __restrict__ b1,
    const float* __restrict__ W2, const float* __restrict__ b2,
    float* __restrict__ out1, float* __restrict__ out2, int N)
{
    constexpr int C4    = C / 4;
    constexpr int COLS4 = (C == 128) ? 2 : 1;
    constexpr int CG    = C4 / COLS4;          // 16
    constexpr int RPT   = 2;
    constexpr int ROWS  = (256 / CG) * RPT;    // 32
    __shared__ __align__(16) float Alds[ROWS][132];

    const int row0 = blockIdx.x * ROWS;
    const int t = threadIdx.x;

    constexpr int LD4 = (ROWS * 32) / 256;     // 4
#pragma unroll
    for (int i = 0; i < LD4; i++) {
        int idx = t + i * 256;
        int r = idx >> 5, kc = idx & 31;
        float4 v = make_float4(0.f, 0.f, 0.f, 0.f);
        int gr = row0 + r;
        if (gr < N) v = reinterpret_cast<const float4*>(A + (size_t)gr * 128)[kc];
        reinterpret_cast<float4*>(&Alds[r][0])[kc] = v;
    }
    __syncthreads();

    const int cg = t % CG;
    const int r0 = (t / CG) * RPT;

    float4 acc1[COLS4][RPT];
    float4 acc2[COLS4][RPT];
#pragma unroll
    for (int c = 0; c < COLS4; c++)
#pragma unroll
        for (int r = 0; r < RPT; r++) {
            acc1[c][r] = make_float4(0.f, 0.f, 0.f, 0.f);
            acc2[c][r] = make_float4(0.f, 0.f, 0.f, 0.f);
        }

    const float4* W1base = reinterpret_cast<const float4*>(W1) + cg * COLS4;
    const float4* W2base = DUAL ? reinterpret_cast<const float4*>(W2) + cg * COLS4
                                : W1base;

    // double-buffered 2-k chunks: 64 chunks total
    float4 w1A[2][COLS4], w2A[2][COLS4], w1B[2][COLS4], w2B[2][COLS4];

    auto ldW = [&](int kc2, float4 (&w1r)[2][COLS4], float4 (&w2r)[2][COLS4]) {
#pragma unroll
        for (int kk = 0; kk < 2; kk++)
#pragma unroll
            for (int c = 0; c < COLS4; c++) {
                w1r[kk][c] = W1base[(kc2 * 2 + kk) * C4 + c];
                if (DUAL) w2r[kk][c] = W2base[(kc2 * 2 + kk) * C4 + c];
            }
    };
    auto comp = [&](int kc2, float4 (&w1r)[2][COLS4], float4 (&w2r)[2][COLS4]) {
#pragma unroll
        for (int kk = 0; kk < 2; kk++) {
            int k = kc2 * 2 + kk;
            float as[RPT];
#pragma unroll
            for (int r = 0; r < RPT; r++) as[r] = Alds[r0 + r][k];
#pragma unroll
            for (int c = 0; c < COLS4; c++) {
                float4 w1 = w1r[kk][c];
#pragma unroll
                for (int r = 0; r < RPT; r++) {
                    acc1[c][r].x = fmaf(as[r], w1.x, acc1[c][r].x);
                    acc1[c][r].y = fmaf(as[r], w1.y, acc1[c][r].y);
                    acc1[c][r].z = fmaf(as[r], w1.z, acc1[c][r].z);
                    acc1[c][r].w = fmaf(as[r], w1.w, acc1[c][r].w);
                }
                if (DUAL) {
                    float4 w2 = w2r[kk][c];
#pragma unroll
                    for (int r = 0; r < RPT; r++) {
                        acc2[c][r].x = fmaf(as[r], w2.x, acc2[c][r].x);
                        acc2[c][r].y = fmaf(as[r], w2.y, acc2[c][r].y);
                        acc2[c][r].z = fmaf(as[r], w2.z, acc2[c][r].z);
                        acc2[c][r].w = fmaf(as[r], w2.w, acc2[c][r].w);
                    }
                }
            }
        }
    };

    ldW(0, w1A, w2A);
#pragma unroll 2
    for (int kc2 = 0; kc2 < 64; kc2 += 2) {
        ldW(kc2 + 1, w1B, w2B);       // prefetch next chunk (independent)
        comp(kc2, w1A, w2A);          // compute current
        if (kc2 + 2 < 64) ldW(kc2 + 2, w1A, w2A);
        comp(kc2 + 1, w1B, w2B);
    }

#pragma unroll
    for (int c = 0; c < COLS4; c++) {
        float4 bb1 = reinterpret_cast<const float4*>(b1)[cg * COLS4 + c];
        float4 bb2 = DUAL ? reinterpret_cast<const float4*>(b2)[cg * COLS4 + c]
                          : make_float4(0.f, 0.f, 0.f, 0.f);
#pragma unroll
        for (int r = 0; r < RPT; r++) {
            int gr = row0 + r0 + r;
            if (gr >= N) continue;
            float4 o = acc1[c][r];
            o.x += bb1.x; o.y += bb1.y; o.z += bb1.z; o.w += bb1.w;
            if (ACT == 1) {
                o.x = gelu_erf(o.x); o.y = gelu_erf(o.y);
                o.z = gelu_erf(o.z); o.w = gelu_erf(o.w);
            }
            reinterpret_cast<float4*>(out1 + (size_t)gr * C)[cg * COLS4 + c] = o;
            if (DUAL) {
                float4 o2 = acc2[c][r];
                o2.x += bb2.x; o2.y += bb2.y; o2.z += bb2.z; o2.w += bb2.w;
                reinterpret_cast<float4*>(out2 + (size_t)gr * C)[cg * COLS4 + c] = o2;
            }
        }
    }
}

// ---------------- CSR build --------------------------------------------------
__global__ __launch_bounds__(256) void hist_kernel(const int* __restrict__ dst,
                                                   int* __restrict__ cnt, int E)
{
    int i = blockIdx.x * 256 + threadIdx.x;
    if (i < E) atomicAdd(&cnt[dst[i]], 1);
}

__global__ __launch_bounds__(256) void scan1_kernel(const int* __restrict__ cnt,
                                                    int* __restrict__ offs,
                                                    int* __restrict__ bsum, int N)
{
    __shared__ int lds[256];
    int t = threadIdx.x;
    int i = blockIdx.x * 256 + t;
    int v = (i < N) ? cnt[i] : 0;
    lds[t] = v;
    __syncthreads();
    int x = v;
    for (int off = 1; off < 256; off <<= 1) {
        int y = (t >= off) ? lds[t - off] : 0;
        __syncthreads();
        x += y;
        lds[t] = x;
        __syncthreads();
    }
    if (i < N) offs[i] = x - v;
    if (t == 255) bsum[blockIdx.x] = x;
}

__global__ __launch_bounds__(256) void scan2_kernel(int* __restrict__ bsum, int NB)
{
    __shared__ int lds[256];
    int t = threadIdx.x;
    int v = (t < NB) ? bsum[t] : 0;
    lds[t] = v;
    __syncthreads();
    int x = v;
    for (int off = 1; off < 256; off <<= 1) {
        int y = (t >= off) ? lds[t - off] : 0;
        __syncthreads();
        x += y;
        lds[t] = x;
        __syncthreads();
    }
    if (t < NB) bsum[t] = x - v;
}

__global__ __launch_bounds__(256) void scan3_kernel(int* __restrict__ offs,
                                                    const int* __restrict__ bsum,
                                                    int* __restrict__ cursor,
                                                    int N, int E)
{
    int i = blockIdx.x * 256 + threadIdx.x;
    if (i < N) {
        int o = offs[i] + bsum[blockIdx.x];
        offs[i] = o;
        cursor[i] = o;
    }
    if (i == 0) offs[N] = E;
}

__global__ __launch_bounds__(256) void scatter_kernel(const int* __restrict__ src,
                                                      const int* __restrict__ dst,
                                                      int* __restrict__ cursor,
                                                      int* __restrict__ csr_src, int E)
{
    int i = blockIdx.x * 256 + threadIdx.x;
    if (i < E) {
        int d = dst[i];
        int pos = atomicAdd(&cursor[d], 1);
        csr_src[pos] = src[i];
    }
}

// ---------------- fused GAT edge-softmax + aggregation -----------------------
// One wave per dst node (wave-uniform via readfirstlane -> scalar CSR walk).
template <int D, int EPI>
__global__ __launch_bounds__(256) void gat_agg(
    const float* __restrict__ q, const float* __restrict__ p,
    const float* __restrict__ a, const float* __restrict__ bvec,
    const int* __restrict__ offs, const int* __restrict__ csr_src,
    float* __restrict__ out, int N)
{
    constexpr int VPL = D / 64;  // 2 (D=128) or 1 (D=64)
    const int lane = threadIdx.x & 63;
    const int node = __builtin_amdgcn_readfirstlane(blockIdx.x * 4 + (threadIdx.x >> 6));
    if (node >= N) return;  // scalar branch

    float qv[VPL], av[VPL], acc[VPL];
#pragma unroll
    for (int v = 0; v < VPL; v++) {
        qv[v] = q[(size_t)node * D + lane * VPL + v];
        av[v] = a[lane * VPL + v];
        acc[v] = 0.f;
    }
    float denom = 0.f;

    const int e0 = offs[node], e1 = offs[node + 1];   // s_load
    int e = e0;

    for (; e + 4 <= e1; e += 4) {
        int s0 = csr_src[e + 0];
        int s1 = csr_src[e + 1];
        int s2 = csr_src[e + 2];
        int s3 = csr_src[e + 3];
        float pv0[VPL], pv1[VPL], pv2[VPL], pv3[VPL];
        if (VPL == 2) {
            float2 t0 = *reinterpret_cast<const float2*>(p + (size_t)s0 * D + lane * 2);
            float2 t1 = *reinterpret_cast<const float2*>(p + (size_t)s1 * D + lane * 2);
            float2 t2 = *reinterpret_cast<const float2*>(p + (size_t)s2 * D + lane * 2);
            float2 t3 = *reinterpret_cast<const float2*>(p + (size_t)s3 * D + lane * 2);
            pv0[0] = t0.x; pv0[1] = t0.y;
            pv1[0] = t1.x; pv1[1] = t1.y;
            pv2[0] = t2.x; pv2[1] = t2.y;
            pv3[0] = t3.x; pv3[1] = t3.y;
        } else {
            pv0[0] = p[(size_t)s0 * D + lane];
            pv1[0] = p[(size_t)s1 * D + lane];
            pv2[0] = p[(size_t)s2 * D + lane];
            pv3[0] = p[(size_t)s3 * D + lane];
        }
        float pa0 = 0.f, pa1 = 0.f, pa2 = 0.f, pa3 = 0.f;
#pragma unroll
        for (int v = 0; v < VPL; v++) {
            float t0 = qv[v] + pv0[v];
            float t1 = qv[v] + pv1[v];
            float t2 = qv[v] + pv2[v];
            float t3 = qv[v] + pv3[v];
            t0 = fmaxf(t0, SLOPE * t0);
            t1 = fmaxf(t1, SLOPE * t1);
            t2 = fmaxf(t2, SLOPE * t2);
            t3 = fmaxf(t3, SLOPE * t3);
            pa0 = fmaf(t0, av[v], pa0);
            pa1 = fmaf(t1, av[v], pa1);
            pa2 = fmaf(t2, av[v], pa2);
            pa3 = fmaf(t3, av[v], pa3);
        }
        float w0 = wave_sum_bcast(pa0);
        float w1 = wave_sum_bcast(pa1);
        float w2 = wave_sum_bcast(pa2);
        float w3 = wave_sum_bcast(pa3);
        float es0 = __expf(w0);
        float es1 = __expf(w1);
        float es2 = __expf(w2);
        float es3 = __expf(w3);
        denom += (es0 + es1) + (es2 + es3);
#pragma unroll
        for (int v = 0; v < VPL; v++) {
            acc[v] = fmaf(es0, pv0[v], acc[v]);
            acc[v] = fmaf(es1, pv1[v], acc[v]);
            acc[v] = fmaf(es2, pv2[v], acc[v]);
            acc[v] = fmaf(es3, pv3[v], acc[v]);
        }
    }
    for (; e < e1; e++) {
        int s0 = csr_src[e];
        float pv0[VPL];
        if (VPL == 2) {
            float2 t0 = *reinterpret_cast<const float2*>(p + (size_t)s0 * D + lane * 2);
            pv0[0] = t0.x; pv0[1] = t0.y;
        } else {
            pv0[0] = p[(size_t)s0 * D + lane];
        }
        float pa0 = 0.f;
#pragma unroll
        for (int v = 0; v < VPL; v++) {
            float t0 = qv[v] + pv0[v];
            t0 = fmaxf(t0, SLOPE * t0);
            pa0 = fmaf(t0, av[v], pa0);
        }
        float es0 = __expf(wave_sum_bcast(pa0));
        denom += es0;
#pragma unroll
        for (int v = 0; v < VPL; v++)
            acc[v] = fmaf(es0, pv0[v], acc[v]);
    }

    float inv = (denom != 0.f) ? 1.f / denom : 0.f;  // zero-degree -> agg = 0
#pragma unroll
    for (int v = 0; v < VPL; v++) {
        float h = acc[v] * inv + bvec[lane * VPL + v];
        acc[v] = (EPI == 0) ? gelu_erf(h) : h;
    }
    if (VPL == 2) {
        float2 o; o.x = acc[0]; o.y = acc[1];
        *reinterpret_cast<float2*>(out + (size_t)node * D + lane * 2) = o;
    } else {
        out[(size_t)node * D + lane] = acc[0];
    }
}

// ---------------- launch ------------------------------------------------------
extern "C" void kernel_launch(void* const* d_in, const int* in_sizes, int n_in,
                              void* d_out, int out_size, void* d_ws, size_t ws_size,
                              hipStream_t stream)
{
    const float* x     = (const float*)d_in[0];
    const float* W0    = (const float*)d_in[1];
    const float* b0    = (const float*)d_in[2];
    const float* Wq1   = (const float*)d_in[3];
    const float* bq1   = (const float*)d_in[4];
    const float* Wp1   = (const float*)d_in[5];
    const float* bp1   = (const float*)d_in[6];
    const float* a1    = (const float*)d_in[7];
    const float* bg2   = (const float*)d_in[8];
    const float* Wq2   = (const float*)d_in[9];
    const float* bq2   = (const float*)d_in[10];
    const float* Wp2   = (const float*)d_in[11];
    const float* bp2   = (const float*)d_in[12];
    const float* a2    = (const float*)d_in[13];
    const float* b_out = (const float*)d_in[14];
    const int*   src   = (const int*)d_in[15];
    const int*   dst   = (const int*)d_in[16];

    const int N = in_sizes[0] / 128;
    const int E = in_sizes[15];
    float* out = (float*)d_out;

    // workspace carve
    float* m_buf = (float*)d_ws;
    float* q_buf = m_buf + (size_t)N * 128;
    float* p_buf = q_buf + (size_t)N * 128;
    int* offs    = (int*)(p_buf + (size_t)N * 128);
    int* cursor  = offs + (N + 1);
    int* csr_src = cursor + N;
    int* bsum    = csr_src + E;

    const int NB = (N + 255) / 256;   // <= 256 assumed

    // CSR build (counts in cursor)
    hipMemsetAsync(cursor, 0, (size_t)N * sizeof(int), stream);
    hist_kernel<<<(E + 255) / 256, 256, 0, stream>>>(dst, cursor, E);
    scan1_kernel<<<NB, 256, 0, stream>>>(cursor, offs, bsum, N);
    scan2_kernel<<<1, 256, 0, stream>>>(bsum, NB);
    scan3_kernel<<<NB, 256, 0, stream>>>(offs, bsum, cursor, N, E);
    scatter_kernel<<<(E + 255) / 256, 256, 0, stream>>>(src, dst, cursor, csr_src, E);

    const int GB = (N + 31) / 32;

    // layer 0: m1 = gelu(x@W0 + b0)
    gemm_k128<128, 1, false><<<GB, 256, 0, stream>>>(x, W0, b0, nullptr, nullptr,
                                                     m_buf, nullptr, N);
    // layer 1 projections (dual)
    gemm_k128<128, 0, true><<<GB, 256, 0, stream>>>(m_buf, Wq1, bq1, Wp1, bp1,
                                                    q_buf, p_buf, N);
    // layer 1 GAT + fused m2 = gelu(h1 + bg2)
    gat_agg<128, 0><<<(N + 3) / 4, 256, 0, stream>>>(q_buf, p_buf, a1, bg2,
                                                     offs, csr_src, m_buf, N);
    // layer 2 projections (dual)
    gemm_k128<64, 0, true><<<GB, 256, 0, stream>>>(m_buf, Wq2, bq2, Wp2, bp2,
                                                   q_buf, p_buf, N);
    // layer 2 GAT + fused + b_out -> d_out
    gat_agg<64, 1><<<(N + 3) / 4, 256, 0, stream>>>(q_buf, p_buf, a2, b_out,
                                                    offs, csr_src, out, N);
}

// Round 5
// 486.049 us; speedup vs baseline: 1.0705x; 1.0705x over previous
//
#include <hip/hip_runtime.h>
#include <hip/hip_bf16.h>
#include <math.h>

// GAT 2-layer fused pipeline for MI355X (gfx950).
// Dims per reference: D_IN=D_H=128, D_OUT=64, SLOPE=0.2. All math fp32.
//
// Round-5 changes:
//  - gemm rewritten: W staged in LDS per 16-k chunk, double-buffered with
//    register prefetch (bulk coalesced global loads; vmcnt wait lands after
//    ~2000 cyc of FMA). Inner loop is pure LDS+FMA: 64 FMA per k (dual)
//    vs 16 ds_read_b128 per 4k. Thread tile = 8 rows x 4 cols (RPT=C4/4).
//    Rounds 3/4 streamed W per-thread from global -> 128 latency-exposed
//    load points per wave (VALUBusy 21%, 96-127us vs 21us FMA floor).
//  - gat_agg / CSR unchanged from round 3.

#define SLOPE 0.2f

__device__ __forceinline__ float gelu_erf(float x) {
    return 0.5f * x * (1.0f + erff(x * 0.70710678118654752f));
}

// Full-wave (64-lane) f32 sum via DPP; result broadcast via readlane 63.
__device__ __forceinline__ float wave_sum_bcast(float x) {
    x += __int_as_float(__builtin_amdgcn_update_dpp(0, __float_as_int(x), 0x111, 0xF, 0xF, true));
    x += __int_as_float(__builtin_amdgcn_update_dpp(0, __float_as_int(x), 0x112, 0xF, 0xF, true));
    x += __int_as_float(__builtin_amdgcn_update_dpp(0, __float_as_int(x), 0x114, 0xF, 0xF, true));
    x += __int_as_float(__builtin_amdgcn_update_dpp(0, __float_as_int(x), 0x118, 0xF, 0xF, true));
    x += __int_as_float(__builtin_amdgcn_update_dpp(0, __float_as_int(x), 0x142, 0xF, 0xF, true));
    x += __int_as_float(__builtin_amdgcn_update_dpp(0, __float_as_int(x), 0x143, 0xF, 0xF, true));
    return __int_as_float(__builtin_amdgcn_readlane(__float_as_int(x), 63));
}

// ---------------- GEMM: out[N,C] = act(A[N,128] @ W[128,C] + bias) ----------
// 256 threads, 64 rows/block. Thread: RPT rows x 4 cols x (1|2 outputs).
// C=128: C4=32, RPT=8.  C=64: C4=16, RPT=4.
template <int C, int ACT, bool DUAL>
__global__ __launch_bounds__(256) void gemm_k128(
    const float* __restrict__ A,
    const float* __restrict__ W1, const float* __restrict__ b1,
    const float* __restrict__ W2, const float* __restrict__ b2,
    float* __restrict__ out1, float* __restrict__ out2, int N)
{
    constexpr int C4   = C / 4;          // float4-cols
    constexpr int RPT  = C4 / 4;         // rows per thread (8 or 4)
    constexpr int ROWS = 64;
    constexpr int NW   = DUAL ? 2 : 1;
    constexpr int KC   = 16;             // k-chunk
    constexpr int NCH  = 128 / KC;       // 8 chunks
    constexpr int PRE  = (C * KC / 4) / 256;  // W float4 per thread per chunk (2 or 1)

    __shared__ __align__(16) float Alds[ROWS][132];
    __shared__ __align__(16) float Wlds[NW][2][KC][C];

    const int row0 = blockIdx.x * ROWS;
    const int t = threadIdx.x;

    // ---- stage A tile (once, coalesced float4) ----
#pragma unroll
    for (int i = 0; i < 8; i++) {
        int idx = t + i * 256;
        int r = idx >> 5, kc = idx & 31;
        float4 v = make_float4(0.f, 0.f, 0.f, 0.f);
        int gr = row0 + r;
        if (gr < N) v = reinterpret_cast<const float4*>(A + (size_t)gr * 128)[kc];
        reinterpret_cast<float4*>(&Alds[r][0])[kc] = v;
    }

    // ---- stage W chunk 0 into buf 0 ----
    const float4* W1v = reinterpret_cast<const float4*>(W1);
    const float4* W2v = DUAL ? reinterpret_cast<const float4*>(W2) : W1v;
    {
#pragma unroll
        for (int i = 0; i < PRE; i++) {
            int idx = t + i * 256;
            int k = idx / C4, c4 = idx % C4;
            reinterpret_cast<float4*>(&Wlds[0][0][k][0])[c4] = W1v[k * C4 + c4];
            if (DUAL)
                reinterpret_cast<float4*>(&Wlds[1][0][k][0])[c4] = W2v[k * C4 + c4];
        }
    }

    const int cg = t % C4;
    const int r0 = (t / C4) * RPT;

    float4 acc[NW][RPT];
#pragma unroll
    for (int o = 0; o < NW; o++)
#pragma unroll
        for (int r = 0; r < RPT; r++) acc[o][r] = make_float4(0.f, 0.f, 0.f, 0.f);

    float4 wpre[NW][PRE];

    for (int ch = 0; ch < NCH; ch++) {
        const int buf = ch & 1;
        // prefetch next W chunk into registers (independent global loads)
        if (ch + 1 < NCH) {
#pragma unroll
            for (int i = 0; i < PRE; i++) {
                int idx = t + i * 256;
                int k = idx / C4, c4 = idx % C4;
                wpre[0][i] = W1v[((ch + 1) * KC + k) * C4 + c4];
                if (DUAL) wpre[1][i] = W2v[((ch + 1) * KC + k) * C4 + c4];
            }
        }
        __syncthreads();   // chunk ch's LDS writes visible; prev compute done

        // ---- compute 16 k's from LDS ----
#pragma unroll
        for (int kk4 = 0; kk4 < KC / 4; kk4++) {
            float4 af[RPT];
#pragma unroll
            for (int r = 0; r < RPT; r++)
                af[r] = *reinterpret_cast<const float4*>(&Alds[r0 + r][ch * KC + kk4 * 4]);
#pragma unroll
            for (int j = 0; j < 4; j++) {
                float as[RPT];
#pragma unroll
                for (int r = 0; r < RPT; r++)
                    as[r] = reinterpret_cast<const float*>(&af[r])[j];
#pragma unroll
                for (int o = 0; o < NW; o++) {
                    float4 w = *reinterpret_cast<const float4*>(
                        &Wlds[o][buf][kk4 * 4 + j][cg * 4]);
#pragma unroll
                    for (int r = 0; r < RPT; r++) {
                        acc[o][r].x = fmaf(as[r], w.x, acc[o][r].x);
                        acc[o][r].y = fmaf(as[r], w.y, acc[o][r].y);
                        acc[o][r].z = fmaf(as[r], w.z, acc[o][r].z);
                        acc[o][r].w = fmaf(as[r], w.w, acc[o][r].w);
                    }
                }
            }
        }

        // ---- store prefetched chunk into other buffer (vmcnt wait here) ----
        if (ch + 1 < NCH) {
#pragma unroll
            for (int i = 0; i < PRE; i++) {
                int idx = t + i * 256;
                int k = idx / C4, c4 = idx % C4;
                reinterpret_cast<float4*>(&Wlds[0][buf ^ 1][k][0])[c4] = wpre[0][i];
                if (DUAL)
                    reinterpret_cast<float4*>(&Wlds[1][buf ^ 1][k][0])[c4] = wpre[1][i];
            }
        }
    }

    // ---- epilogue ----
#pragma unroll
    for (int o = 0; o < NW; o++) {
        const float* bb = (o == 0) ? b1 : b2;
        float* op = (o == 0) ? out1 : out2;
        float4 bv = reinterpret_cast<const float4*>(bb)[cg];
#pragma unroll
        for (int r = 0; r < RPT; r++) {
            int gr = row0 + r0 + r;
            if (gr >= N) continue;
            float4 v = acc[o][r];
            v.x += bv.x; v.y += bv.y; v.z += bv.z; v.w += bv.w;
            if (ACT == 1 && o == 0) {
                v.x = gelu_erf(v.x); v.y = gelu_erf(v.y);
                v.z = gelu_erf(v.z); v.w = gelu_erf(v.w);
            }
            reinterpret_cast<float4*>(op + (size_t)gr * C)[cg] = v;
        }
    }
}

// ---------------- CSR build --------------------------------------------------
__global__ __launch_bounds__(256) void hist_kernel(const int* __restrict__ dst,
                                                   int* __restrict__ cnt, int E)
{
    int i = blockIdx.x * 256 + threadIdx.x;
    if (i < E) atomicAdd(&cnt[dst[i]], 1);
}

__global__ __launch_bounds__(256) void scan1_kernel(const int* __restrict__ cnt,
                                                    int* __restrict__ offs,
                                                    int* __restrict__ bsum, int N)
{
    __shared__ int lds[256];
    int t = threadIdx.x;
    int i = blockIdx.x * 256 + t;
    int v = (i < N) ? cnt[i] : 0;
    lds[t] = v;
    __syncthreads();
    int x = v;
    for (int off = 1; off < 256; off <<= 1) {
        int y = (t >= off) ? lds[t - off] : 0;
        __syncthreads();
        x += y;
        lds[t] = x;
        __syncthreads();
    }
    if (i < N) offs[i] = x - v;
    if (t == 255) bsum[blockIdx.x] = x;
}

__global__ __launch_bounds__(256) void scan2_kernel(int* __restrict__ bsum, int NB)
{
    __shared__ int lds[256];
    int t = threadIdx.x;
    int v = (t < NB) ? bsum[t] : 0;
    lds[t] = v;
    __syncthreads();
    int x = v;
    for (int off = 1; off < 256; off <<= 1) {
        int y = (t >= off) ? lds[t - off] : 0;
        __syncthreads();
        x += y;
        lds[t] = x;
        __syncthreads();
    }
    if (t < NB) bsum[t] = x - v;
}

__global__ __launch_bounds__(256) void scan3_kernel(int* __restrict__ offs,
                                                    const int* __restrict__ bsum,
                                                    int* __restrict__ cursor,
                                                    int N, int E)
{
    int i = blockIdx.x * 256 + threadIdx.x;
    if (i < N) {
        int o = offs[i] + bsum[blockIdx.x];
        offs[i] = o;
        cursor[i] = o;
    }
    if (i == 0) offs[N] = E;
}

__global__ __launch_bounds__(256) void scatter_kernel(const int* __restrict__ src,
                                                      const int* __restrict__ dst,
                                                      int* __restrict__ cursor,
                                                      int* __restrict__ csr_src, int E)
{
    int i = blockIdx.x * 256 + threadIdx.x;
    if (i < E) {
        int d = dst[i];
        int pos = atomicAdd(&cursor[d], 1);
        csr_src[pos] = src[i];
    }
}

// ---------------- fused GAT edge-softmax + aggregation -----------------------
// One wave per dst node (wave-uniform via readfirstlane -> scalar CSR walk).
template <int D, int EPI>
__global__ __launch_bounds__(256) void gat_agg(
    const float* __restrict__ q, const float* __restrict__ p,
    const float* __restrict__ a, const float* __restrict__ bvec,
    const int* __restrict__ offs, const int* __restrict__ csr_src,
    float* __restrict__ out, int N)
{
    constexpr int VPL = D / 64;  // 2 (D=128) or 1 (D=64)
    const int lane = threadIdx.x & 63;
    const int node = __builtin_amdgcn_readfirstlane(blockIdx.x * 4 + (threadIdx.x >> 6));
    if (node >= N) return;  // scalar branch

    float qv[VPL], av[VPL], acc[VPL];
#pragma unroll
    for (int v = 0; v < VPL; v++) {
        qv[v] = q[(size_t)node * D + lane * VPL + v];
        av[v] = a[lane * VPL + v];
        acc[v] = 0.f;
    }
    float denom = 0.f;

    const int e0 = offs[node], e1 = offs[node + 1];   // s_load
    int e = e0;

    for (; e + 4 <= e1; e += 4) {
        int s0 = csr_src[e + 0];
        int s1 = csr_src[e + 1];
        int s2 = csr_src[e + 2];
        int s3 = csr_src[e + 3];
        float pv0[VPL], pv1[VPL], pv2[VPL], pv3[VPL];
        if (VPL == 2) {
            float2 t0 = *reinterpret_cast<const float2*>(p + (size_t)s0 * D + lane * 2);
            float2 t1 = *reinterpret_cast<const float2*>(p + (size_t)s1 * D + lane * 2);
            float2 t2 = *reinterpret_cast<const float2*>(p + (size_t)s2 * D + lane * 2);
            float2 t3 = *reinterpret_cast<const float2*>(p + (size_t)s3 * D + lane * 2);
            pv0[0] = t0.x; pv0[1] = t0.y;
            pv1[0] = t1.x; pv1[1] = t1.y;
            pv2[0] = t2.x; pv2[1] = t2.y;
            pv3[0] = t3.x; pv3[1] = t3.y;
        } else {
            pv0[0] = p[(size_t)s0 * D + lane];
            pv1[0] = p[(size_t)s1 * D + lane];
            pv2[0] = p[(size_t)s2 * D + lane];
            pv3[0] = p[(size_t)s3 * D + lane];
        }
        float pa0 = 0.f, pa1 = 0.f, pa2 = 0.f, pa3 = 0.f;
#pragma unroll
        for (int v = 0; v < VPL; v++) {
            float t0 = qv[v] + pv0[v];
            float t1 = qv[v] + pv1[v];
            float t2 = qv[v] + pv2[v];
            float t3 = qv[v] + pv3[v];
            t0 = fmaxf(t0, SLOPE * t0);
            t1 = fmaxf(t1, SLOPE * t1);
            t2 = fmaxf(t2, SLOPE * t2);
            t3 = fmaxf(t3, SLOPE * t3);
            pa0 = fmaf(t0, av[v], pa0);
            pa1 = fmaf(t1, av[v], pa1);
            pa2 = fmaf(t2, av[v], pa2);
            pa3 = fmaf(t3, av[v], pa3);
        }
        float w0 = wave_sum_bcast(pa0);
        float w1 = wave_sum_bcast(pa1);
        float w2 = wave_sum_bcast(pa2);
        float w3 = wave_sum_bcast(pa3);
        float es0 = __expf(w0);
        float es1 = __expf(w1);
        float es2 = __expf(w2);
        float es3 = __expf(w3);
        denom += (es0 + es1) + (es2 + es3);
#pragma unroll
        for (int v = 0; v < VPL; v++) {
            acc[v] = fmaf(es0, pv0[v], acc[v]);
            acc[v] = fmaf(es1, pv1[v], acc[v]);
            acc[v] = fmaf(es2, pv2[v], acc[v]);
            acc[v] = fmaf(es3, pv3[v], acc[v]);
        }
    }
    for (; e < e1; e++) {
        int s0 = csr_src[e];
        float pv0[VPL];
        if (VPL == 2) {
            float2 t0 = *reinterpret_cast<const float2*>(p + (size_t)s0 * D + lane * 2);
            pv0[0] = t0.x; pv0[1] = t0.y;
        } else {
            pv0[0] = p[(size_t)s0 * D + lane];
        }
        float pa0 = 0.f;
#pragma unroll
        for (int v = 0; v < VPL; v++) {
            float t0 = qv[v] + pv0[v];
            t0 = fmaxf(t0, SLOPE * t0);
            pa0 = fmaf(t0, av[v], pa0);
        }
        float es0 = __expf(wave_sum_bcast(pa0));
        denom += es0;
#pragma unroll
        for (int v = 0; v < VPL; v++)
            acc[v] = fmaf(es0, pv0[v], acc[v]);
    }

    float inv = (denom != 0.f) ? 1.f / denom : 0.f;  // zero-degree -> agg = 0
#pragma unroll
    for (int v = 0; v < VPL; v++) {
        float h = acc[v] * inv + bvec[lane * VPL + v];
        acc[v] = (EPI == 0) ? gelu_erf(h) : h;
    }
    if (VPL == 2) {
        float2 o; o.x = acc[0]; o.y = acc[1];
        *reinterpret_cast<float2*>(out + (size_t)node * D + lane * 2) = o;
    } else {
        out[(size_t)node * D + lane] = acc[0];
    }
}

// ---------------- launch ------------------------------------------------------
extern "C" void kernel_launch(void* const* d_in, const int* in_sizes, int n_in,
                              void* d_out, int out_size, void* d_ws, size_t ws_size,
                              hipStream_t stream)
{
    const float* x     = (const float*)d_in[0];
    const float* W0    = (const float*)d_in[1];
    const float* b0    = (const float*)d_in[2];
    const float* Wq1   = (const float*)d_in[3];
    const float* bq1   = (const float*)d_in[4];
    const float* Wp1   = (const float*)d_in[5];
    const float* bp1   = (const float*)d_in[6];
    const float* a1    = (const float*)d_in[7];
    const float* bg2   = (const float*)d_in[8];
    const float* Wq2   = (const float*)d_in[9];
    const float* bq2   = (const float*)d_in[10];
    const float* Wp2   = (const float*)d_in[11];
    const float* bp2   = (const float*)d_in[12];
    const float* a2    = (const float*)d_in[13];
    const float* b_out = (const float*)d_in[14];
    const int*   src   = (const int*)d_in[15];
    const int*   dst   = (const int*)d_in[16];

    const int N = in_sizes[0] / 128;
    const int E = in_sizes[15];
    float* out = (float*)d_out;

    // workspace carve
    float* m_buf = (float*)d_ws;
    float* q_buf = m_buf + (size_t)N * 128;
    float* p_buf = q_buf + (size_t)N * 128;
    int* offs    = (int*)(p_buf + (size_t)N * 128);
    int* cursor  = offs + (N + 1);
    int* csr_src = cursor + N;
    int* bsum    = csr_src + E;

    const int NB = (N + 255) / 256;   // <= 256 assumed

    // CSR build (counts in cursor)
    hipMemsetAsync(cursor, 0, (size_t)N * sizeof(int), stream);
    hist_kernel<<<(E + 255) / 256, 256, 0, stream>>>(dst, cursor, E);
    scan1_kernel<<<NB, 256, 0, stream>>>(cursor, offs, bsum, N);
    scan2_kernel<<<1, 256, 0, stream>>>(bsum, NB);
    scan3_kernel<<<NB, 256, 0, stream>>>(offs, bsum, cursor, N, E);
    scatter_kernel<<<(E + 255) / 256, 256, 0, stream>>>(src, dst, cursor, csr_src, E);

    const int GB = (N + 63) / 64;

    // layer 0: m1 = gelu(x@W0 + b0)
    gemm_k128<128, 1, false><<<GB, 256, 0, stream>>>(x, W0, b0, nullptr, nullptr,
                                                     m_buf, nullptr, N);
    // layer 1 projections (dual)
    gemm_k128<128, 0, true><<<GB, 256, 0, stream>>>(m_buf, Wq1, bq1, Wp1, bp1,
                                                    q_buf, p_buf, N);
    // layer 1 GAT + fused m2 = gelu(h1 + bg2)
    gat_agg<128, 0><<<(N + 3) / 4, 256, 0, stream>>>(q_buf, p_buf, a1, bg2,
                                                     offs, csr_src, m_buf, N);
    // layer 2 projections (dual)
    gemm_k128<64, 0, true><<<GB, 256, 0, stream>>>(m_buf, Wq2, bq2, Wp2, bp2,
                                                   q_buf, p_buf, N);
    // layer 2 GAT + fused + b_out -> d_out
    gat_agg<64, 1><<<(N + 3) / 4, 256, 0, stream>>>(q_buf, p_buf, a2, b_out,
                                                    offs, csr_src, out, N);
}

// Round 6
// 402.128 us; speedup vs baseline: 1.2939x; 1.2087x over previous
//
#include <hip/hip_runtime.h>
#include <hip/hip_bf16.h>
#include <math.h>

// GAT 2-layer fused pipeline for MI355X (gfx950).
// Dims per reference: D_IN=D_H=128, D_OUT=64, SLOPE=0.2.
//
// Round-6: GEMMs moved to MFMA (16x16x32 bf16) with split-precision
// (A,W = bf16 hi + bf16 lo; C = Ah*Wh + Al*Wh + Ah*Wl, fp32 accumulate)
// -> fp32-grade accuracy on the idle matrix pipe. W prepacked per call
// into B-fragment lane layout (hi/lo) so B-loads are coalesced 16B/lane
// L2-resident dwordx4. A tile converted to hi/lo bf16 in LDS (stride 136
// -> 2-way bank aliasing only, free). Rounds 3-5 showed fp32 scalar-FMA
// GEMM stuck at 5x its 21us FMA floor (latency/LDS/occupancy walls).
// gat_agg / CSR unchanged from round 3.

#define SLOPE 0.2f

typedef __attribute__((ext_vector_type(8))) __bf16 bf16x8;
typedef __attribute__((ext_vector_type(4))) float f32x4;

__device__ __forceinline__ float gelu_erf(float x) {
    return 0.5f * x * (1.0f + erff(x * 0.70710678118654752f));
}

__device__ __forceinline__ unsigned short f2bf(float f) {  // RNE
    unsigned int u = __float_as_uint(f);
    return (unsigned short)((u + 0x7fffu + ((u >> 16) & 1u)) >> 16);
}

// Full-wave (64-lane) f32 sum via DPP; result broadcast via readlane 63.
__device__ __forceinline__ float wave_sum_bcast(float x) {
    x += __int_as_float(__builtin_amdgcn_update_dpp(0, __float_as_int(x), 0x111, 0xF, 0xF, true));
    x += __int_as_float(__builtin_amdgcn_update_dpp(0, __float_as_int(x), 0x112, 0xF, 0xF, true));
    x += __int_as_float(__builtin_amdgcn_update_dpp(0, __float_as_int(x), 0x114, 0xF, 0xF, true));
    x += __int_as_float(__builtin_amdgcn_update_dpp(0, __float_as_int(x), 0x118, 0xF, 0xF, true));
    x += __int_as_float(__builtin_amdgcn_update_dpp(0, __float_as_int(x), 0x142, 0xF, 0xF, true));
    x += __int_as_float(__builtin_amdgcn_update_dpp(0, __float_as_int(x), 0x143, 0xF, 0xF, true));
    return __int_as_float(__builtin_amdgcn_readlane(__float_as_int(x), 63));
}

// ---------------- weight prepack: fp32 [128,C] -> bf16 hi/lo B-fragments ----
// Pack index i = ((ct*4+ks)*64 + lane)*8 + j  maps to  W[k][n],
// k = ks*32 + (lane>>4)*8 + j,  n = ct*16 + (lane&15).  hi at [i], lo at [CE+i].
__global__ __launch_bounds__(256) void pack_w(
    const float* __restrict__ W0,  const float* __restrict__ Wq1,
    const float* __restrict__ Wp1, const float* __restrict__ Wq2,
    const float* __restrict__ Wp2,
    unsigned short* __restrict__ P0,  unsigned short* __restrict__ Pq1,
    unsigned short* __restrict__ Pp1, unsigned short* __restrict__ Pq2,
    unsigned short* __restrict__ Pp2)
{
    const float* W; unsigned short* P; int C;
    switch (blockIdx.y) {
        case 0:  W = W0;  P = P0;  C = 128; break;
        case 1:  W = Wq1; P = Pq1; C = 128; break;
        case 2:  W = Wp1; P = Pp1; C = 128; break;
        case 3:  W = Wq2; P = Pq2; C = 64;  break;
        default: W = Wp2; P = Pp2; C = 64;  break;
    }
    int i = blockIdx.x * 256 + threadIdx.x;
    int CE = C * 128;
    if (i >= CE) return;
    int j = i & 7, l = (i >> 3) & 63, ks = (i >> 9) & 3, ct = i >> 11;
    int k = ks * 32 + ((l >> 4) << 3) + j;
    int n = ct * 16 + (l & 15);
    float v = W[k * C + n];
    unsigned short hb = f2bf(v);
    float hf = __uint_as_float((unsigned int)hb << 16);
    unsigned short lb = f2bf(v - hf);
    P[i] = hb;
    P[CE + i] = lb;
}

// ---------------- MFMA GEMM: out[N,C] = act(A[N,128] @ W[128,C] + bias) -----
// 256 threads = 4 waves, 64 rows/block; wave w -> rows w*16..w*16+15, all C.
template <int C, int ACT, bool DUAL>
__global__ __launch_bounds__(256) void mfma_gemm(
    const float* __restrict__ A,
    const unsigned short* __restrict__ P1, const float* __restrict__ b1,
    const unsigned short* __restrict__ P2, const float* __restrict__ b2,
    float* __restrict__ out1, float* __restrict__ out2, int N)
{
    constexpr int CT = C / 16;        // col tiles (8 or 4)
    constexpr int NW = DUAL ? 2 : 1;
    constexpr int CE = C * 128;       // elems per packed part

    __shared__ unsigned short Ahi[64][136];  // stride 136*2B: 2-way aliasing, free
    __shared__ unsigned short Alo[64][136];

    const int t = threadIdx.x;
    const int row0 = blockIdx.x * 64;

    // ---- stage A tile: fp32 global -> hi/lo bf16 LDS ----
#pragma unroll
    for (int i = 0; i < 8; i++) {
        int idx = t + i * 256;                 // 2048 = 64 rows * 32 float4
        int r = idx >> 5, c4 = idx & 31;
        float4 v = make_float4(0.f, 0.f, 0.f, 0.f);
        if (row0 + r < N)
            v = reinterpret_cast<const float4*>(A + (size_t)(row0 + r) * 128)[c4];
        const float* f = reinterpret_cast<const float*>(&v);
        unsigned int hp[2], lp[2];
        unsigned short h[4], lo[4];
#pragma unroll
        for (int e = 0; e < 4; e++) {
            h[e] = f2bf(f[e]);
            float hf = __uint_as_float((unsigned int)h[e] << 16);
            lo[e] = f2bf(f[e] - hf);
        }
        hp[0] = (unsigned int)h[0] | ((unsigned int)h[1] << 16);
        hp[1] = (unsigned int)h[2] | ((unsigned int)h[3] << 16);
        lp[0] = (unsigned int)lo[0] | ((unsigned int)lo[1] << 16);
        lp[1] = (unsigned int)lo[2] | ((unsigned int)lo[3] << 16);
        *reinterpret_cast<uint2*>(&Ahi[r][c4 * 4]) = make_uint2(hp[0], hp[1]);
        *reinterpret_cast<uint2*>(&Alo[r][c4 * 4]) = make_uint2(lp[0], lp[1]);
    }
    __syncthreads();

    const int lane = t & 63;
    const int w = t >> 6;
    const int mrow = w * 16 + (lane & 15);     // A-fragment row
    const int koff = (lane >> 4) * 8;          // A/B-fragment k offset

    f32x4 acc[NW][CT];
#pragma unroll
    for (int o = 0; o < NW; o++)
#pragma unroll
        for (int c = 0; c < CT; c++) acc[o][c] = (f32x4){0.f, 0.f, 0.f, 0.f};

    const unsigned short* p1l = P1 + lane * 8;
    const unsigned short* p2l = DUAL ? (P2 + lane * 8) : p1l;

#pragma unroll
    for (int ks = 0; ks < 4; ks++) {
        bf16x8 ah = *reinterpret_cast<const bf16x8*>(&Ahi[mrow][ks * 32 + koff]);
        bf16x8 al = *reinterpret_cast<const bf16x8*>(&Alo[mrow][ks * 32 + koff]);
#pragma unroll
        for (int ct = 0; ct < CT; ct++) {
            const int off = (ct * 4 + ks) * 512;   // 64 lanes * 8 elems
            bf16x8 bh1 = *reinterpret_cast<const bf16x8*>(p1l + off);
            bf16x8 bl1 = *reinterpret_cast<const bf16x8*>(p1l + CE + off);
            acc[0][ct] = __builtin_amdgcn_mfma_f32_16x16x32_bf16(ah, bh1, acc[0][ct], 0, 0, 0);
            acc[0][ct] = __builtin_amdgcn_mfma_f32_16x16x32_bf16(al, bh1, acc[0][ct], 0, 0, 0);
            acc[0][ct] = __builtin_amdgcn_mfma_f32_16x16x32_bf16(ah, bl1, acc[0][ct], 0, 0, 0);
            if (DUAL) {
                bf16x8 bh2 = *reinterpret_cast<const bf16x8*>(p2l + off);
                bf16x8 bl2 = *reinterpret_cast<const bf16x8*>(p2l + CE + off);
                acc[1][ct] = __builtin_amdgcn_mfma_f32_16x16x32_bf16(ah, bh2, acc[1][ct], 0, 0, 0);
                acc[1][ct] = __builtin_amdgcn_mfma_f32_16x16x32_bf16(al, bh2, acc[1][ct], 0, 0, 0);
                acc[1][ct] = __builtin_amdgcn_mfma_f32_16x16x32_bf16(ah, bl2, acc[1][ct], 0, 0, 0);
            }
        }
    }

    // ---- epilogue: C/D layout col=lane&15, row=(lane>>4)*4+reg ----
    const int orow = w * 16 + (lane >> 4) * 4;
#pragma unroll
    for (int o = 0; o < NW; o++) {
        const float* bb = o ? b2 : b1;
        float* op = o ? out2 : out1;
#pragma unroll
        for (int ct = 0; ct < CT; ct++) {
            int col = ct * 16 + (lane & 15);
            float bv = bb[col];
#pragma unroll
            for (int r = 0; r < 4; r++) {
                int gr = row0 + orow + r;
                if (gr < N) {
                    float v = acc[o][ct][r] + bv;
                    if (ACT == 1 && o == 0) v = gelu_erf(v);
                    op[(size_t)gr * C + col] = v;
                }
            }
        }
    }
}

// ---------------- CSR build --------------------------------------------------
__global__ __launch_bounds__(256) void hist_kernel(const int* __restrict__ dst,
                                                   int* __restrict__ cnt, int E)
{
    int i = blockIdx.x * 256 + threadIdx.x;
    if (i < E) atomicAdd(&cnt[dst[i]], 1);
}

__global__ __launch_bounds__(256) void scan1_kernel(const int* __restrict__ cnt,
                                                    int* __restrict__ offs,
                                                    int* __restrict__ bsum, int N)
{
    __shared__ int lds[256];
    int t = threadIdx.x;
    int i = blockIdx.x * 256 + t;
    int v = (i < N) ? cnt[i] : 0;
    lds[t] = v;
    __syncthreads();
    int x = v;
    for (int off = 1; off < 256; off <<= 1) {
        int y = (t >= off) ? lds[t - off] : 0;
        __syncthreads();
        x += y;
        lds[t] = x;
        __syncthreads();
    }
    if (i < N) offs[i] = x - v;
    if (t == 255) bsum[blockIdx.x] = x;
}

__global__ __launch_bounds__(256) void scan2_kernel(int* __restrict__ bsum, int NB)
{
    __shared__ int lds[256];
    int t = threadIdx.x;
    int v = (t < NB) ? bsum[t] : 0;
    lds[t] = v;
    __syncthreads();
    int x = v;
    for (int off = 1; off < 256; off <<= 1) {
        int y = (t >= off) ? lds[t - off] : 0;
        __syncthreads();
        x += y;
        lds[t] = x;
        __syncthreads();
    }
    if (t < NB) bsum[t] = x - v;
}

__global__ __launch_bounds__(256) void scan3_kernel(int* __restrict__ offs,
                                                    const int* __restrict__ bsum,
                                                    int* __restrict__ cursor,
                                                    int N, int E)
{
    int i = blockIdx.x * 256 + threadIdx.x;
    if (i < N) {
        int o = offs[i] + bsum[blockIdx.x];
        offs[i] = o;
        cursor[i] = o;
    }
    if (i == 0) offs[N] = E;
}

__global__ __launch_bounds__(256) void scatter_kernel(const int* __restrict__ src,
                                                      const int* __restrict__ dst,
                                                      int* __restrict__ cursor,
                                                      int* __restrict__ csr_src, int E)
{
    int i = blockIdx.x * 256 + threadIdx.x;
    if (i < E) {
        int d = dst[i];
        int pos = atomicAdd(&cursor[d], 1);
        csr_src[pos] = src[i];
    }
}

// ---------------- fused GAT edge-softmax + aggregation -----------------------
// One wave per dst node (wave-uniform via readfirstlane -> scalar CSR walk).
template <int D, int EPI>
__global__ __launch_bounds__(256) void gat_agg(
    const float* __restrict__ q, const float* __restrict__ p,
    const float* __restrict__ a, const float* __restrict__ bvec,
    const int* __restrict__ offs, const int* __restrict__ csr_src,
    float* __restrict__ out, int N)
{
    constexpr int VPL = D / 64;  // 2 (D=128) or 1 (D=64)
    const int lane = threadIdx.x & 63;
    const int node = __builtin_amdgcn_readfirstlane(blockIdx.x * 4 + (threadIdx.x >> 6));
    if (node >= N) return;  // scalar branch

    float qv[VPL], av[VPL], acc[VPL];
#pragma unroll
    for (int v = 0; v < VPL; v++) {
        qv[v] = q[(size_t)node * D + lane * VPL + v];
        av[v] = a[lane * VPL + v];
        acc[v] = 0.f;
    }
    float denom = 0.f;

    const int e0 = offs[node], e1 = offs[node + 1];   // s_load
    int e = e0;

    for (; e + 4 <= e1; e += 4) {
        int s0 = csr_src[e + 0];
        int s1 = csr_src[e + 1];
        int s2 = csr_src[e + 2];
        int s3 = csr_src[e + 3];
        float pv0[VPL], pv1[VPL], pv2[VPL], pv3[VPL];
        if (VPL == 2) {
            float2 t0 = *reinterpret_cast<const float2*>(p + (size_t)s0 * D + lane * 2);
            float2 t1 = *reinterpret_cast<const float2*>(p + (size_t)s1 * D + lane * 2);
            float2 t2 = *reinterpret_cast<const float2*>(p + (size_t)s2 * D + lane * 2);
            float2 t3 = *reinterpret_cast<const float2*>(p + (size_t)s3 * D + lane * 2);
            pv0[0] = t0.x; pv0[1] = t0.y;
            pv1[0] = t1.x; pv1[1] = t1.y;
            pv2[0] = t2.x; pv2[1] = t2.y;
            pv3[0] = t3.x; pv3[1] = t3.y;
        } else {
            pv0[0] = p[(size_t)s0 * D + lane];
            pv1[0] = p[(size_t)s1 * D + lane];
            pv2[0] = p[(size_t)s2 * D + lane];
            pv3[0] = p[(size_t)s3 * D + lane];
        }
        float pa0 = 0.f, pa1 = 0.f, pa2 = 0.f, pa3 = 0.f;
#pragma unroll
        for (int v = 0; v < VPL; v++) {
            float t0 = qv[v] + pv0[v];
            float t1 = qv[v] + pv1[v];
            float t2 = qv[v] + pv2[v];
            float t3 = qv[v] + pv3[v];
            t0 = fmaxf(t0, SLOPE * t0);
            t1 = fmaxf(t1, SLOPE * t1);
            t2 = fmaxf(t2, SLOPE * t2);
            t3 = fmaxf(t3, SLOPE * t3);
            pa0 = fmaf(t0, av[v], pa0);
            pa1 = fmaf(t1, av[v], pa1);
            pa2 = fmaf(t2, av[v], pa2);
            pa3 = fmaf(t3, av[v], pa3);
        }
        float w0 = wave_sum_bcast(pa0);
        float w1 = wave_sum_bcast(pa1);
        float w2 = wave_sum_bcast(pa2);
        float w3 = wave_sum_bcast(pa3);
        float es0 = __expf(w0);
        float es1 = __expf(w1);
        float es2 = __expf(w2);
        float es3 = __expf(w3);
        denom += (es0 + es1) + (es2 + es3);
#pragma unroll
        for (int v = 0; v < VPL; v++) {
            acc[v] = fmaf(es0, pv0[v], acc[v]);
            acc[v] = fmaf(es1, pv1[v], acc[v]);
            acc[v] = fmaf(es2, pv2[v], acc[v]);
            acc[v] = fmaf(es3, pv3[v], acc[v]);
        }
    }
    for (; e < e1; e++) {
        int s0 = csr_src[e];
        float pv0[VPL];
        if (VPL == 2) {
            float2 t0 = *reinterpret_cast<const float2*>(p + (size_t)s0 * D + lane * 2);
            pv0[0] = t0.x; pv0[1] = t0.y;
        } else {
            pv0[0] = p[(size_t)s0 * D + lane];
        }
        float pa0 = 0.f;
#pragma unroll
        for (int v = 0; v < VPL; v++) {
            float t0 = qv[v] + pv0[v];
            t0 = fmaxf(t0, SLOPE * t0);
            pa0 = fmaf(t0, av[v], pa0);
        }
        float es0 = __expf(wave_sum_bcast(pa0));
        denom += es0;
#pragma unroll
        for (int v = 0; v < VPL; v++)
            acc[v] = fmaf(es0, pv0[v], acc[v]);
    }

    float inv = (denom != 0.f) ? 1.f / denom : 0.f;  // zero-degree -> agg = 0
#pragma unroll
    for (int v = 0; v < VPL; v++) {
        float h = acc[v] * inv + bvec[lane * VPL + v];
        acc[v] = (EPI == 0) ? gelu_erf(h) : h;
    }
    if (VPL == 2) {
        float2 o; o.x = acc[0]; o.y = acc[1];
        *reinterpret_cast<float2*>(out + (size_t)node * D + lane * 2) = o;
    } else {
        out[(size_t)node * D + lane] = acc[0];
    }
}

// ---------------- launch ------------------------------------------------------
extern "C" void kernel_launch(void* const* d_in, const int* in_sizes, int n_in,
                              void* d_out, int out_size, void* d_ws, size_t ws_size,
                              hipStream_t stream)
{
    const float* x     = (const float*)d_in[0];
    const float* W0    = (const float*)d_in[1];
    const float* b0    = (const float*)d_in[2];
    const float* Wq1   = (const float*)d_in[3];
    const float* bq1   = (const float*)d_in[4];
    const float* Wp1   = (const float*)d_in[5];
    const float* bp1   = (const float*)d_in[6];
    const float* a1    = (const float*)d_in[7];
    const float* bg2   = (const float*)d_in[8];
    const float* Wq2   = (const float*)d_in[9];
    const float* bq2   = (const float*)d_in[10];
    const float* Wp2   = (const float*)d_in[11];
    const float* bp2   = (const float*)d_in[12];
    const float* a2    = (const float*)d_in[13];
    const float* b_out = (const float*)d_in[14];
    const int*   src   = (const int*)d_in[15];
    const int*   dst   = (const int*)d_in[16];

    const int N = in_sizes[0] / 128;
    const int E = in_sizes[15];
    float* out = (float*)d_out;

    // workspace carve
    float* m_buf = (float*)d_ws;
    float* q_buf = m_buf + (size_t)N * 128;
    float* p_buf = q_buf + (size_t)N * 128;
    unsigned short* P0  = (unsigned short*)(p_buf + (size_t)N * 128);
    unsigned short* Pq1 = P0  + 128 * 128 * 2;
    unsigned short* Pp1 = Pq1 + 128 * 128 * 2;
    unsigned short* Pq2 = Pp1 + 128 * 128 * 2;
    unsigned short* Pp2 = Pq2 + 128 * 64 * 2;
    int* offs    = (int*)(Pp2 + 128 * 64 * 2);
    int* cursor  = offs + (N + 1);
    int* csr_src = cursor + N;
    int* bsum    = csr_src + E;

    const int NB = (N + 255) / 256;   // <= 256 assumed

    // weight prepack (independent of CSR)
    pack_w<<<dim3(64, 5), 256, 0, stream>>>(W0, Wq1, Wp1, Wq2, Wp2,
                                            P0, Pq1, Pp1, Pq2, Pp2);

    // CSR build (counts in cursor)
    hipMemsetAsync(cursor, 0, (size_t)N * sizeof(int), stream);
    hist_kernel<<<(E + 255) / 256, 256, 0, stream>>>(dst, cursor, E);
    scan1_kernel<<<NB, 256, 0, stream>>>(cursor, offs, bsum, N);
    scan2_kernel<<<1, 256, 0, stream>>>(bsum, NB);
    scan3_kernel<<<NB, 256, 0, stream>>>(offs, bsum, cursor, N, E);
    scatter_kernel<<<(E + 255) / 256, 256, 0, stream>>>(src, dst, cursor, csr_src, E);

    const int GB = (N + 63) / 64;

    // layer 0: m1 = gelu(x@W0 + b0)
    mfma_gemm<128, 1, false><<<GB, 256, 0, stream>>>(x, P0, b0, nullptr, nullptr,
                                                     m_buf, nullptr, N);
    // layer 1 projections (dual)
    mfma_gemm<128, 0, true><<<GB, 256, 0, stream>>>(m_buf, Pq1, bq1, Pp1, bp1,
                                                    q_buf, p_buf, N);
    // layer 1 GAT + fused m2 = gelu(h1 + bg2)
    gat_agg<128, 0><<<(N + 3) / 4, 256, 0, stream>>>(q_buf, p_buf, a1, bg2,
                                                     offs, csr_src, m_buf, N);
    // layer 2 projections (dual)
    mfma_gemm<64, 0, true><<<GB, 256, 0, stream>>>(m_buf, Pq2, bq2, Pp2, bp2,
                                                   q_buf, p_buf, N);
    // layer 2 GAT + fused + b_out -> d_out
    gat_agg<64, 1><<<(N + 3) / 4, 256, 0, stream>>>(q_buf, p_buf, a2, b_out,
                                                    offs, csr_src, out, N);
}